// Round 1
// baseline (222.848 us; speedup 1.0000x reference)
//
#include <hip/hip_runtime.h>

typedef unsigned short u16;
typedef float f32x4 __attribute__((ext_vector_type(4)));
typedef __bf16 bf16x8 __attribute__((ext_vector_type(8)));
typedef unsigned short u16x8 __attribute__((ext_vector_type(8)));

// f32 -> bf16 round-to-nearest-even
__device__ __forceinline__ u16 f2bf(float f) {
  unsigned u = __float_as_uint(f);
  unsigned r = u + 0x7fffu + ((u >> 16) & 1u);
  return (u16)(r >> 16);
}

// ---------------------------------------------------------------------------
// proj_q: Qb[b][t][c8] (bf16), t in 0..16383.  grid (256,2), block 256
// ---------------------------------------------------------------------------
__global__ void proj_q_kernel(const float* __restrict__ x, const float* __restrict__ Wq,
                              const float* __restrict__ bq, u16* __restrict__ Qb) {
  __shared__ float xl[256][64];   // x tile [c][t]
  __shared__ float wl[32 * 256];  // Wq
  const int tid = threadIdx.x;
  const int t0 = blockIdx.x * 64, b = blockIdx.y;
  for (int i = tid; i < 4096; i += 256) {
    int c = i >> 4, j = i & 15;
    float4 v = *reinterpret_cast<const float4*>(x + ((size_t)(b * 256 + c)) * 16384 + t0 + j * 4);
    *reinterpret_cast<float4*>(&xl[c][j * 4]) = v;
  }
  for (int i = tid; i < 2048; i += 256)
    *reinterpret_cast<float4*>(&wl[i * 4]) = *reinterpret_cast<const float4*>(Wq + i * 4);
  __syncthreads();
  const int tok = tid & 63, g8 = tid >> 6;  // 4 groups x 8 c8
  float acc[8];
#pragma unroll
  for (int j = 0; j < 8; ++j) acc[j] = bq[g8 * 8 + j];
  for (int c = 0; c < 256; ++c) {
    float xv = xl[c][tok];
#pragma unroll
    for (int j = 0; j < 8; ++j) acc[j] += xv * wl[(g8 * 8 + j) * 256 + c];
  }
  u16x8 o;
#pragma unroll
  for (int j = 0; j < 8; ++j) o[j] = f2bf(acc[j]);
  *reinterpret_cast<u16x8*>(Qb + ((size_t)(b * 16384 + t0 + tok)) * 32 + g8 * 8) = o;
}

// ---------------------------------------------------------------------------
// proj_k: Kt[b][s][c8] (bf16), s in 0..4095 (pooled 64x64). grid (64,2), block 256
// pooling fused: xl[c][sx] = mean 2x2 of x rows (2*sy, 2*sy+1)
// ---------------------------------------------------------------------------
__global__ void proj_k_kernel(const float* __restrict__ x, const float* __restrict__ Wk,
                              const float* __restrict__ bk, u16* __restrict__ Kt) {
  __shared__ float xl[256][64];
  __shared__ float wl[32 * 256];
  const int tid = threadIdx.x;
  const int sy = blockIdx.x, b = blockIdx.y;
  for (int i = tid; i < 8192; i += 256) {
    int c = i >> 5, jj = i & 31;
    size_t base = ((size_t)(b * 256 + c)) * 16384 + (size_t)sy * 256;
    float4 r0 = *reinterpret_cast<const float4*>(x + base + jj * 4);
    float4 r1 = *reinterpret_cast<const float4*>(x + base + 128 + jj * 4);
    xl[c][jj * 2] = (r0.x + r0.y + r1.x + r1.y) * 0.25f;
    xl[c][jj * 2 + 1] = (r0.z + r0.w + r1.z + r1.w) * 0.25f;
  }
  for (int i = tid; i < 2048; i += 256)
    *reinterpret_cast<float4*>(&wl[i * 4]) = *reinterpret_cast<const float4*>(Wk + i * 4);
  __syncthreads();
  const int sx = tid & 63, g8 = tid >> 6;
  float acc[8];
#pragma unroll
  for (int j = 0; j < 8; ++j) acc[j] = bk[g8 * 8 + j];
  for (int c = 0; c < 256; ++c) {
    float xv = xl[c][sx];
#pragma unroll
    for (int j = 0; j < 8; ++j) acc[j] += xv * wl[(g8 * 8 + j) * 256 + c];
  }
  u16x8 o;
#pragma unroll
  for (int j = 0; j < 8; ++j) o[j] = f2bf(acc[j]);
  *reinterpret_cast<u16x8*>(Kt + ((size_t)(b * 4096 + sy * 64 + sx)) * 32 + g8 * 8) = o;
}

// ---------------------------------------------------------------------------
// proj_v: Vb[b][c][s] (bf16). grid (64,2,2), block 256.
// z splits output channels: oc passes  (z*4 .. z*4+3), 32 ch per pass.
// ---------------------------------------------------------------------------
__global__ void proj_v_kernel(const float* __restrict__ x, const float* __restrict__ Wv,
                              const float* __restrict__ bvp, u16* __restrict__ Vb) {
  __shared__ float xl[256][64];
  __shared__ float wvl[32 * 256];
  const int tid = threadIdx.x;
  const int sy = blockIdx.x, b = blockIdx.y, z = blockIdx.z;
  for (int i = tid; i < 8192; i += 256) {
    int c = i >> 5, jj = i & 31;
    size_t base = ((size_t)(b * 256 + c)) * 16384 + (size_t)sy * 256;
    float4 r0 = *reinterpret_cast<const float4*>(x + base + jj * 4);
    float4 r1 = *reinterpret_cast<const float4*>(x + base + 128 + jj * 4);
    xl[c][jj * 2] = (r0.x + r0.y + r1.x + r1.y) * 0.25f;
    xl[c][jj * 2 + 1] = (r0.z + r0.w + r1.z + r1.w) * 0.25f;
  }
  const int s = tid & 63, grp = tid >> 6;
  for (int p = 0; p < 4; ++p) {
    int oc = z * 4 + p;  // 32-channel chunk index
    __syncthreads();     // protects wvl reuse (and first-pass xl)
    for (int i = tid; i < 2048; i += 256)
      *reinterpret_cast<float4*>(&wvl[i * 4]) =
          *reinterpret_cast<const float4*>(Wv + (size_t)oc * 8192 + i * 4);
    __syncthreads();
    int cb = oc * 32 + grp * 8;
    float acc[8];
#pragma unroll
    for (int j = 0; j < 8; ++j) acc[j] = bvp[cb + j];
    for (int c = 0; c < 256; ++c) {
      float xv = xl[c][s];
#pragma unroll
      for (int j = 0; j < 8; ++j) acc[j] += xv * wvl[(grp * 8 + j) * 256 + c];
    }
#pragma unroll
    for (int j = 0; j < 8; ++j)
      Vb[((size_t)(b * 256 + cb + j)) * 4096 + sy * 64 + s] = f2bf(acc[j]);
  }
}

// ---------------------------------------------------------------------------
// attn: fused  softmax(Q Kt / sqrt(32)) * V^T  + residual.
// grid (256, 2), block 256 (4 waves). Block = 64 Q tokens, full 256 channels.
// Wave w: QK for keys [w*16, w*16+16); PV for channels [w*64, w*64+64).
// No max-subtraction (logits ~ N(0,0.5^2), safe in fp32).
// LDS tiles XOR-swizzled; p transposed via LDS round-trip.
// ---------------------------------------------------------------------------
__global__ __launch_bounds__(256, 2) void attn_kernel(
    const u16* __restrict__ Qb, const u16* __restrict__ Kt, const u16* __restrict__ Vb,
    const float* __restrict__ x, const float* __restrict__ gamma, float* __restrict__ out) {
  __shared__ __align__(16) u16 q_lds[64 * 32];   // [tok][c8]   4KB
  __shared__ __align__(16) u16 k_lds[64 * 32];   // [key][c8]   4KB
  __shared__ __align__(16) u16 v_lds[256 * 64];  // [ch][key]  32KB
  __shared__ __align__(16) u16 p_lds[64 * 64];   // [tok][key]  8KB
  __shared__ float lred[4][64];

  const int tid = threadIdx.x;
  const int lane = tid & 63, w = tid >> 6;
  const int l15 = lane & 15, l4 = lane >> 4;
  const int t0 = blockIdx.x * 64, b = blockIdx.y;

  // load Q tile once (256 chunks of 8 u16, one per thread)
  {
    int tok = tid >> 2, j = tid & 3;
    u16x8 v = *reinterpret_cast<const u16x8*>(Qb + ((size_t)(b * 16384 + t0 + tok)) * 32 + j * 8);
    *reinterpret_cast<u16x8*>(q_lds + (tok * 4 + (j ^ (tok & 3))) * 8) = v;
  }

  f32x4 acc[4][4] = {};  // [m-tile][n-tile], tokens x channels
  float lsum[16] = {};   // row-sum partials, [mt*4+r]
  const float SCALE = 0.17677669529663687f;  // 1/sqrt(32)

  for (int kt = 0; kt < 64; ++kt) {
    __syncthreads();  // previous iter's PV reads done (also covers initial q_lds)
    // stage K tile (64 keys x 32 c8): one 16B chunk per thread
    {
      int key = tid >> 2, j = tid & 3;
      u16x8 v =
          *reinterpret_cast<const u16x8*>(Kt + ((size_t)(b * 4096 + kt * 64 + key)) * 32 + j * 8);
      *reinterpret_cast<u16x8*>(k_lds + (key * 4 + (j ^ (key & 3))) * 8) = v;
    }
    // stage V tile (256 ch x 64 keys): 8 chunks per thread
#pragma unroll
    for (int r = 0; r < 8; ++r) {
      int i = tid + r * 256;
      int ch = i >> 3, j = i & 7;
      u16x8 v = *reinterpret_cast<const u16x8*>(Vb + ((size_t)(b * 256 + ch)) * 4096 + kt * 64 + j * 8);
      *reinterpret_cast<u16x8*>(v_lds + (ch * 8 + (j ^ (ch & 7))) * 8) = v;
    }
    __syncthreads();

    // ---- QK: S[tok][key], this wave's 16 keys ----
    const int key = w * 16 + l15;
    bf16x8 bk_ = *reinterpret_cast<const bf16x8*>(k_lds + (key * 4 + (l4 ^ (key & 3))) * 8);
    f32x4 zero = {0.0f, 0.0f, 0.0f, 0.0f};
    f32x4 sfr[4];
#pragma unroll
    for (int mt = 0; mt < 4; ++mt) {
      int tokr = mt * 16 + l15;  // A-operand row
      bf16x8 aq = *reinterpret_cast<const bf16x8*>(q_lds + (tokr * 4 + (l4 ^ (tokr & 3))) * 8);
      sfr[mt] = __builtin_amdgcn_mfma_f32_16x16x32_bf16(aq, bk_, zero, 0, 0, 0);
    }
    // exp + row-sum partials + write P (transposed layout for PV A-operand)
#pragma unroll
    for (int mt = 0; mt < 4; ++mt) {
#pragma unroll
      for (int r = 0; r < 4; ++r) {
        float p = __expf(sfr[mt][r] * SCALE);
        lsum[mt * 4 + r] += p;
        int tok = mt * 16 + l4 * 4 + r;  // C-layout row
        p_lds[tok * 64 + (((key >> 3) ^ (tok & 7)) * 8) + (key & 7)] = f2bf(p);
      }
    }
    __syncthreads();

    // ---- PV: acc[tok][ch] += P * V^T, channels w*64..w*64+63 ----
#pragma unroll
    for (int ks = 0; ks < 2; ++ks) {
      bf16x8 bfr[4], afr[4];
#pragma unroll
      for (int nt = 0; nt < 4; ++nt) {
        int ch = w * 64 + nt * 16 + l15;
        bfr[nt] = *reinterpret_cast<const bf16x8*>(v_lds + (ch * 8 + ((ks * 4 + l4) ^ (ch & 7))) * 8);
      }
#pragma unroll
      for (int mt = 0; mt < 4; ++mt) {
        int tok = mt * 16 + l15;
        afr[mt] = *reinterpret_cast<const bf16x8*>(p_lds + (tok * 8 + ((ks * 4 + l4) ^ (tok & 7))) * 8);
      }
#pragma unroll
      for (int mt = 0; mt < 4; ++mt)
#pragma unroll
        for (int nt = 0; nt < 4; ++nt)
          acc[mt][nt] = __builtin_amdgcn_mfma_f32_16x16x32_bf16(afr[mt], bfr[nt], acc[mt][nt], 0, 0, 0);
    }
  }

  // ---- finish row sums: reduce over the 16 key-column lanes, then waves ----
#pragma unroll
  for (int d = 1; d < 16; d <<= 1)
#pragma unroll
    for (int i = 0; i < 16; ++i) lsum[i] += __shfl_xor(lsum[i], d, 64);
  if (l15 == 0) {
#pragma unroll
    for (int mt = 0; mt < 4; ++mt)
#pragma unroll
      for (int r = 0; r < 4; ++r) lred[w][mt * 16 + l4 * 4 + r] = lsum[mt * 4 + r];
  }
  __syncthreads();

  const float g = gamma[0];
  float linv[16];
#pragma unroll
  for (int mt = 0; mt < 4; ++mt)
#pragma unroll
    for (int r = 0; r < 4; ++r) {
      int tok = mt * 16 + l4 * 4 + r;
      linv[mt * 4 + r] = 1.0f / (lred[0][tok] + lred[1][tok] + lred[2][tok] + lred[3][tok]);
    }
  // ---- epilogue: out = gamma * acc / l + x ; float4 along tokens ----
#pragma unroll
  for (int mt = 0; mt < 4; ++mt) {
#pragma unroll
    for (int nt = 0; nt < 4; ++nt) {
      int ch = w * 64 + nt * 16 + l15;
      size_t idx = ((size_t)(b * 256 + ch)) * 16384 + t0 + mt * 16 + l4 * 4;
      float4 xr = *reinterpret_cast<const float4*>(x + idx);
      float4 o;
      o.x = g * acc[mt][nt][0] * linv[mt * 4 + 0] + xr.x;
      o.y = g * acc[mt][nt][1] * linv[mt * 4 + 1] + xr.y;
      o.z = g * acc[mt][nt][2] * linv[mt * 4 + 2] + xr.z;
      o.w = g * acc[mt][nt][3] * linv[mt * 4 + 3] + xr.w;
      *reinterpret_cast<float4*>(out + idx) = o;
    }
  }
}

// ---------------------------------------------------------------------------
extern "C" void kernel_launch(void* const* d_in, const int* in_sizes, int n_in,
                              void* d_out, int out_size, void* d_ws, size_t ws_size,
                              hipStream_t stream) {
  const float* x = (const float*)d_in[0];
  const float* Wq = (const float*)d_in[1];
  const float* bq = (const float*)d_in[2];
  const float* Wk = (const float*)d_in[3];
  const float* bk = (const float*)d_in[4];
  const float* Wv = (const float*)d_in[5];
  const float* bv = (const float*)d_in[6];
  const float* gamma = (const float*)d_in[7];
  float* out = (float*)d_out;

  char* ws = (char*)d_ws;
  u16* Qb = (u16*)ws;                                    // 2 MB  : [2][16384][32]
  u16* Kt = (u16*)(ws + (2u << 20));                     // 512 KB: [2][4096][32]
  u16* Vb = (u16*)(ws + (2u << 20) + (512u << 10));      // 4 MB  : [2][256][4096]

  proj_q_kernel<<<dim3(256, 2), 256, 0, stream>>>(x, Wq, bq, Qb);
  proj_k_kernel<<<dim3(64, 2), 256, 0, stream>>>(x, Wk, bk, Kt);
  proj_v_kernel<<<dim3(64, 2, 2), 256, 0, stream>>>(x, Wv, bv, Vb);
  attn_kernel<<<dim3(256, 2), 256, 0, stream>>>(Qb, Kt, Vb, x, gamma, out);
}